// Round 5
// baseline (92.602 us; speedup 1.0000x reference)
//
#include <hip/hip_runtime.h>
#include <math.h>

namespace {
constexpr int Bn = 8192, Pn = 128, Dn = 128;
constexpr int BT = 64, PT = 32;                   // block tile: 64 b-rows x 32 p-rows
constexpr float MAXN = 1.0f - 1e-5f;              // (1-PROJ_EPS)/sqrt(c)
constexpr float CLAMPV = 16.63553233343869f;      // log(2/eps32)
constexpr float SMOOTH = 50.0f;
}

// ---------------- per-p prep: projected bias, cx, bw, 1/a_norm, lambda_p*a_norm
__global__ void prep_p_kernel(const float* __restrict__ weight,
                              const float* __restrict__ bias,
                              float* __restrict__ bp,
                              float* __restrict__ pp) {
  const int p = blockIdx.x;
  const int lane = threadIdx.x;  // 0..63
  const float* br = bias + p * Dn;
  const float* wr = weight + p * Dn;
  float b0 = br[lane], b1 = br[lane + 64];
  float w0 = wr[lane], w1 = wr[lane + 64];
  double nb2 = (double)b0 * b0 + (double)b1 * b1;
#pragma unroll
  for (int off = 32; off; off >>= 1) nb2 += __shfl_xor(nb2, off);
  double norm = sqrt(nb2);
  if (norm < 1e-15) norm = 1e-15;
  double scl = (norm > (double)MAXN) ? (double)MAXN / norm : 1.0;
  float bp0 = (float)((double)b0 * scl);
  float bp1 = (float)((double)b1 * scl);
  bp[p * Dn + lane] = bp0;
  bp[p * Dn + lane + 64] = bp1;
  double p2 = nb2 * scl * scl;
  double cx = 1.0 - p2;                 // coef_x = 1 - c*||p||^2
  double bwl = (double)bp0 * w0 + (double)bp1 * w1;
  double w2l = (double)w0 * w0 + (double)w1 * w1;
#pragma unroll
  for (int off = 32; off; off >>= 1) {
    bwl += __shfl_xor(bwl, off);
    w2l += __shfl_xor(w2l, off);
  }
  if (lane == 0) {
    double an = cx * sqrt(w2l);         // ||a|| = (1-p2)*||w||
    if (an < 1e-15) an = 1e-15;
    pp[p]          = (float)cx;
    pp[Pn + p]     = (float)bwl;        // <bias_proj, w>
    pp[2 * Pn + p] = (float)(1.0 / an);
    pp[3 * Pn + p] = (float)(2.0 / cx * an);  // lambda_p * a_norm
  }
}

// ---------------- per-b prep: x2 and 2/(1-x2), f64-accurate (1-x2 ~ 2e-5)
__global__ void prep_x_kernel(const float* __restrict__ x, float* __restrict__ xb) {
  const int row = blockIdx.x * 4 + (threadIdx.x >> 6);
  const int lane = threadIdx.x & 63;
  const float* xr = x + row * Dn;
  float x0 = xr[lane], x1 = xr[lane + 64];
  double s = (double)x0 * x0 + (double)x1 * x1;
#pragma unroll
  for (int off = 32; off; off >>= 1) s += __shfl_xor(s, off);
  if (lane == 0) {
    xb[row] = (float)s;
    xb[Bn + row] = (float)(2.0 / (1.0 - s));
  }
}

// ---------------- main: stage-once LDS (x,w,bp all swizzled, 64KB), ONE barrier,
// 2-deep register-pipelined pure-LDS K-stream, micro 4(b) x 2(p), fused epilogue.

// load fragment set for k-block kb (compile-time under full unroll)
#define LOADF(kb, X0, X1, X2, X3, W0, W1, B0, B1)            \
  {                                                          \
    const int kx_ = (kb) ^ sx, kw_ = (kb) ^ sw;              \
    X0 = xt4[xbase0 + kx_]; X1 = xt4[xbase1 + kx_];          \
    X2 = xt4[xbase2 + kx_]; X3 = xt4[xbase3 + kx_];          \
    W0 = wt4[wbase0 + kw_]; W1 = wt4[wbase1 + kw_];          \
    B0 = bt4[wbase0 + kw_]; B1 = bt4[wbase1 + kw_];          \
  }

#define FMA8(X0, X1, X2, X3, W0, W1, B0, B1)                 \
  {                                                          \
    float4 xf_[4] = {X0, X1, X2, X3};                        \
    float4 wf_[2] = {W0, W1};                                \
    float4 bf_[2] = {B0, B1};                                \
    _Pragma("unroll") for (int i = 0; i < 4; ++i) {          \
      _Pragma("unroll") for (int j = 0; j < 2; ++j) {        \
        accw[i][j] = fmaf(xf_[i].x, wf_[j].x, accw[i][j]);   \
        accw[i][j] = fmaf(xf_[i].y, wf_[j].y, accw[i][j]);   \
        accw[i][j] = fmaf(xf_[i].z, wf_[j].z, accw[i][j]);   \
        accw[i][j] = fmaf(xf_[i].w, wf_[j].w, accw[i][j]);   \
        accb[i][j] = fmaf(xf_[i].x, bf_[j].x, accb[i][j]);   \
        accb[i][j] = fmaf(xf_[i].y, bf_[j].y, accb[i][j]);   \
        accb[i][j] = fmaf(xf_[i].z, bf_[j].z, accb[i][j]);   \
        accb[i][j] = fmaf(xf_[i].w, bf_[j].w, accb[i][j]);   \
      }                                                      \
    }                                                        \
  }

__global__ __launch_bounds__(256, 2)
void main_kernel(const float* __restrict__ x,
                 const float* __restrict__ weight,
                 const float* __restrict__ bpg,
                 const float* __restrict__ pp,
                 const float* __restrict__ xb,
                 float* __restrict__ out) {
  __shared__ float4 xt4[BT * 32];   // 32 KB
  __shared__ float4 wt4[PT * 32];   // 16 KB
  __shared__ float4 bt4[PT * 32];   // 16 KB  -> 64 KB total, 2 blocks/CU

  const int tid = threadIdx.x;
  const int tx = tid & 15;          // p-direction (micro 2)
  const int ty = tid >> 4;          // b-direction (micro 4)
  const int b0 = blockIdx.x * BT;
  const int p0 = blockIdx.y * PT;

  // ---- stage all tiles; global reads linear & coalesced; swizzle on LDS write:
  // slot(r,c) = r*32 + (c ^ ((r>>2)&7))
#pragma unroll
  for (int t = 0; t < 8; ++t) {
    int F = t * 256 + tid;
    int r = F >> 5, c = F & 31;
    xt4[r * 32 + (c ^ ((r >> 2) & 7))] =
        *reinterpret_cast<const float4*>(x + (size_t)(b0 + r) * Dn + c * 4);
  }
#pragma unroll
  for (int t = 0; t < 4; ++t) {
    int F = t * 256 + tid;
    int r = F >> 5, c = F & 31;
    wt4[r * 32 + (c ^ ((r >> 2) & 7))] =
        *reinterpret_cast<const float4*>(weight + (size_t)(p0 + r) * Dn + c * 4);
    bt4[r * 32 + (c ^ ((r >> 2) & 7))] =
        *reinterpret_cast<const float4*>(bpg + (size_t)(p0 + r) * Dn + c * 4);
  }
  __syncthreads();

  float accw[4][2] = {};
  float accb[4][2] = {};
  const int sx = ty & 7;            // (4ty+i)>>2 == ty
  const int sw = tx >> 1;           // (2tx+j)>>2 == tx>>1
  const int xbase0 = (4 * ty + 0) * 32, xbase1 = (4 * ty + 1) * 32;
  const int xbase2 = (4 * ty + 2) * 32, xbase3 = (4 * ty + 3) * 32;
  const int wbase0 = (2 * tx + 0) * 32, wbase1 = (2 * tx + 1) * 32;

  float4 xA0, xA1, xA2, xA3, wA0, wA1, bA0, bA1;
  float4 xB0, xB1, xB2, xB3, wB0, wB1, bB0, bB1;

  LOADF(0, xA0, xA1, xA2, xA3, wA0, wA1, bA0, bA1);
#pragma unroll
  for (int kb = 0; kb < 32; kb += 2) {
    LOADF(kb + 1, xB0, xB1, xB2, xB3, wB0, wB1, bB0, bB1);
    FMA8(xA0, xA1, xA2, xA3, wA0, wA1, bA0, bA1);
    if (kb + 2 < 32) {
      LOADF(kb + 2, xA0, xA1, xA2, xA3, wA0, wA1, bA0, bA1);
    }
    FMA8(xB0, xB1, xB2, xB3, wB0, wB1, bB0, bB1);
  }

  // ---- epilogue: per-(b,p) scalar math (Mobius denominator cancels analytically)
  float cxj[2], bwj[2], iaj[2], soj[2], x2i[4], fbi[4];
#pragma unroll
  for (int j = 0; j < 2; ++j) {
    int p = p0 + 2 * tx + j;
    cxj[j] = pp[p]; bwj[j] = pp[Pn + p]; iaj[j] = pp[2 * Pn + p]; soj[j] = pp[3 * Pn + p];
  }
#pragma unroll
  for (int i = 0; i < 4; ++i) {
    int b = b0 + 4 * ty + i;
    x2i[i] = xb[b]; fbi[i] = xb[Bn + b];
  }

#pragma unroll
  for (int i = 0; i < 4; ++i) {
    int b = b0 + 4 * ty + i;
    float res[2];
#pragma unroll
    for (int j = 0; j < 2; ++j) {
      float sb = accb[i][j];                     // <bias_proj, x>
      float xw = accw[i][j];                     // <w, x>
      float coefp = 1.0f + x2i[i] - 2.0f * sb;   // 1 + 2c*dot + c*x2
      float X = cxj[j] * xw - coefp * bwj[j];
      float arg = X * fbi[i] * iaj[j];           // den cancels
      float z1 = SMOOTH * (arg + CLAMPV);
      float z2 = SMOOTH * (arg - CLAMPV);
      float sp1 = fmaxf(z1, 0.0f) + log1pf(expf(-fabsf(z1)));
      float sp2 = fmaxf(z2, 0.0f) + log1pf(expf(-fabsf(z2)));
      float argc = -CLAMPV + (sp1 - sp2) * (1.0f / SMOOTH);
      res[j] = soj[j] * asinhf(argc);
    }
    *reinterpret_cast<float2*>(out + (size_t)b * Pn + p0 + 2 * tx) =
        make_float2(res[0], res[1]);
  }
}

extern "C" void kernel_launch(void* const* d_in, const int* in_sizes, int n_in,
                              void* d_out, int out_size, void* d_ws, size_t ws_size,
                              hipStream_t stream) {
  const float* x = (const float*)d_in[0];
  const float* w = (const float*)d_in[1];
  const float* bias = (const float*)d_in[2];
  float* out = (float*)d_out;
  float* ws = (float*)d_ws;
  float* bpd = ws;                // [P][D] projected bias
  float* pp = bpd + Pn * Dn;      // 4*P per-p params
  float* xb = pp + 4 * Pn;        // 2*B per-b params

  hipLaunchKernelGGL(prep_p_kernel, dim3(Pn), dim3(64), 0, stream, w, bias, bpd, pp);
  hipLaunchKernelGGL(prep_x_kernel, dim3(Bn / 4), dim3(256), 0, stream, x, xb);
  hipLaunchKernelGGL(main_kernel, dim3(Bn / BT, Pn / PT), dim3(256), 0, stream,
                     x, w, bpd, pp, xb, out);
}

// Round 6
// 39.914 us; speedup vs baseline: 2.3201x; 2.3201x over previous
//
#include <hip/hip_runtime.h>
#include <math.h>

namespace {
constexpr int Bn = 8192, Pn = 128, Dn = 128;
constexpr int BT = 64, PT = 32;                   // block tile: 64 b-rows x 32 p-rows
constexpr float MAXN = 1.0f - 1e-5f;              // (1-PROJ_EPS)/sqrt(c)
constexpr float CLAMPV = 16.63553233343869f;      // log(2/eps32)
constexpr float SMOOTH = 50.0f;
}

// ---------------- per-p prep: projected bias, cx, bw, 1/a_norm, lambda_p*a_norm
__global__ void prep_p_kernel(const float* __restrict__ weight,
                              const float* __restrict__ bias,
                              float* __restrict__ bp,
                              float* __restrict__ pp) {
  const int p = blockIdx.x;
  const int lane = threadIdx.x;  // 0..63
  const float* br = bias + p * Dn;
  const float* wr = weight + p * Dn;
  float b0 = br[lane], b1 = br[lane + 64];
  float w0 = wr[lane], w1 = wr[lane + 64];
  double nb2 = (double)b0 * b0 + (double)b1 * b1;
#pragma unroll
  for (int off = 32; off; off >>= 1) nb2 += __shfl_xor(nb2, off);
  double norm = sqrt(nb2);
  if (norm < 1e-15) norm = 1e-15;
  double scl = (norm > (double)MAXN) ? (double)MAXN / norm : 1.0;
  float bp0 = (float)((double)b0 * scl);
  float bp1 = (float)((double)b1 * scl);
  bp[p * Dn + lane] = bp0;
  bp[p * Dn + lane + 64] = bp1;
  double p2 = nb2 * scl * scl;
  double cx = 1.0 - p2;                 // coef_x = 1 - c*||p||^2
  double bwl = (double)bp0 * w0 + (double)bp1 * w1;
  double w2l = (double)w0 * w0 + (double)w1 * w1;
#pragma unroll
  for (int off = 32; off; off >>= 1) {
    bwl += __shfl_xor(bwl, off);
    w2l += __shfl_xor(w2l, off);
  }
  if (lane == 0) {
    double an = cx * sqrt(w2l);         // ||a|| = (1-p2)*||w||
    if (an < 1e-15) an = 1e-15;
    pp[p]          = (float)cx;
    pp[Pn + p]     = (float)bwl;        // <bias_proj, w>
    pp[2 * Pn + p] = (float)(1.0 / an);
    pp[3 * Pn + p] = (float)(2.0 / cx * an);  // lambda_p * a_norm
  }
}

// ---------------- per-b prep: x2 and 2/(1-x2), f64-accurate (1-x2 ~ 2e-5)
__global__ void prep_x_kernel(const float* __restrict__ x, float* __restrict__ xb) {
  const int row = blockIdx.x * 4 + (threadIdx.x >> 6);
  const int lane = threadIdx.x & 63;
  const float* xr = x + row * Dn;
  float x0 = xr[lane], x1 = xr[lane + 64];
  double s = (double)x0 * x0 + (double)x1 * x1;
#pragma unroll
  for (int off = 32; off; off >>= 1) s += __shfl_xor(s, off);
  if (lane == 0) {
    xb[row] = (float)s;
    xb[Bn + row] = (float)(2.0 / (1.0 - s));
  }
}

// ---------------- main: 64x32 tile, 512 threads = 2 teams k-splitting D=128.
// Stage-once LDS (padded stride 33 float4), micro 4(b) x 2(p) per thread,
// bf from global (L1-resident slab), partial-sum exchange via reused LDS.
__global__ __launch_bounds__(512, 4)
void main_kernel(const float* __restrict__ x,
                 const float* __restrict__ weight,
                 const float* __restrict__ bpg,
                 const float* __restrict__ pp,
                 const float* __restrict__ xb,
                 float* __restrict__ out) {
  __shared__ float4 xs4[64 * 33];   // 33.8 KB, row stride 33 float4 (bank-stagger)
  __shared__ float4 ws4[32 * 33];   // 16.9 KB

  const int tid = threadIdx.x;
  const int tx = tid & 15;          // p-direction (micro 2)
  const int ty = (tid >> 4) & 15;   // b-direction (micro 4)
  const int team = tid >> 8;        // 0: k=0..63, 1: k=64..127
  const int b0 = blockIdx.x * BT;
  const int p0 = blockIdx.y * PT;

  // ---- stage x (2048 float4) and w (1024 float4); coalesced, padded stride
#pragma unroll
  for (int q = 0; q < 4; ++q) {
    int t = q * 512 + tid;
    int r = t >> 5, c = t & 31;
    xs4[r * 33 + c] = *reinterpret_cast<const float4*>(x + (size_t)(b0 + r) * Dn + c * 4);
  }
#pragma unroll
  for (int q = 0; q < 2; ++q) {
    int t = q * 512 + tid;
    int r = t >> 5, c = t & 31;
    ws4[r * 33 + c] = *reinterpret_cast<const float4*>(weight + (size_t)(p0 + r) * Dn + c * 4);
  }
  __syncthreads();

  float accw[4][2] = {};
  float accb[4][2] = {};
  const float4* bprow0 =
      reinterpret_cast<const float4*>(bpg + (size_t)(p0 + 2 * tx) * Dn) + team * 16;
  const float4* bprow1 =
      reinterpret_cast<const float4*>(bpg + (size_t)(p0 + 2 * tx + 1) * Dn) + team * 16;
  const int xbase = (4 * ty) * 33 + team * 16;   // + i*33 + kb
  const int wbase = (2 * tx) * 33 + team * 16;   // + j*33 + kb

#pragma unroll 4
  for (int kb = 0; kb < 16; ++kb) {
    float4 xf[4], wf[2], bf[2];
#pragma unroll
    for (int i = 0; i < 4; ++i) xf[i] = xs4[xbase + i * 33 + kb];
#pragma unroll
    for (int j = 0; j < 2; ++j) wf[j] = ws4[wbase + j * 33 + kb];
    bf[0] = bprow0[kb];
    bf[1] = bprow1[kb];
#pragma unroll
    for (int i = 0; i < 4; ++i) {
#pragma unroll
      for (int j = 0; j < 2; ++j) {
        accw[i][j] = fmaf(xf[i].x, wf[j].x, accw[i][j]);
        accw[i][j] = fmaf(xf[i].y, wf[j].y, accw[i][j]);
        accw[i][j] = fmaf(xf[i].z, wf[j].z, accw[i][j]);
        accw[i][j] = fmaf(xf[i].w, wf[j].w, accw[i][j]);
        accb[i][j] = fmaf(xf[i].x, bf[j].x, accb[i][j]);
        accb[i][j] = fmaf(xf[i].y, bf[j].y, accb[i][j]);
        accb[i][j] = fmaf(xf[i].z, bf[j].z, accb[i][j]);
        accb[i][j] = fmaf(xf[i].w, bf[j].w, accb[i][j]);
      }
    }
  }

  // ---- combine k-halves: team1 parks partials in (now-dead) xs4, team0 sums.
  __syncthreads();                  // all LDS tile reads complete
  if (team == 1) {
#pragma unroll
    for (int i = 0; i < 4; ++i)
      xs4[(tid & 255) * 4 + i] =
          make_float4(accw[i][0], accw[i][1], accb[i][0], accb[i][1]);
  }
  __syncthreads();

  if (team == 0) {
    // ---- epilogue: per-(b,p) scalar math (Mobius denominator cancels)
    float cxj[2], bwj[2], iaj[2], soj[2], x2i[4], fbi[4];
#pragma unroll
    for (int j = 0; j < 2; ++j) {
      int p = p0 + 2 * tx + j;
      cxj[j] = pp[p]; bwj[j] = pp[Pn + p]; iaj[j] = pp[2 * Pn + p]; soj[j] = pp[3 * Pn + p];
    }
#pragma unroll
    for (int i = 0; i < 4; ++i) {
      int b = b0 + 4 * ty + i;
      x2i[i] = xb[b]; fbi[i] = xb[Bn + b];
    }
#pragma unroll
    for (int i = 0; i < 4; ++i) {
      float4 part = xs4[tid * 4 + i];
      float sw0 = accw[i][0] + part.x;
      float sw1 = accw[i][1] + part.y;
      float sb0 = accb[i][0] + part.z;
      float sb1 = accb[i][1] + part.w;
      float swv[2] = {sw0, sw1};
      float sbv[2] = {sb0, sb1};
      int b = b0 + 4 * ty + i;
      float res[2];
#pragma unroll
      for (int j = 0; j < 2; ++j) {
        float coefp = 1.0f + x2i[i] - 2.0f * sbv[j];   // 1 + 2c*dot + c*x2
        float X = cxj[j] * swv[j] - coefp * bwj[j];
        float arg = X * fbi[i] * iaj[j];               // den cancels analytically
        float z1 = SMOOTH * (arg + CLAMPV);
        float z2 = SMOOTH * (arg - CLAMPV);
        float sp1 = fmaxf(z1, 0.0f) + log1pf(expf(-fabsf(z1)));
        float sp2 = fmaxf(z2, 0.0f) + log1pf(expf(-fabsf(z2)));
        float argc = -CLAMPV + (sp1 - sp2) * (1.0f / SMOOTH);
        res[j] = soj[j] * asinhf(argc);
      }
      *reinterpret_cast<float2*>(out + (size_t)b * Pn + p0 + 2 * tx) =
          make_float2(res[0], res[1]);
    }
  }
}

extern "C" void kernel_launch(void* const* d_in, const int* in_sizes, int n_in,
                              void* d_out, int out_size, void* d_ws, size_t ws_size,
                              hipStream_t stream) {
  const float* x = (const float*)d_in[0];
  const float* w = (const float*)d_in[1];
  const float* bias = (const float*)d_in[2];
  float* out = (float*)d_out;
  float* ws = (float*)d_ws;
  float* bpd = ws;                // [P][D] projected bias
  float* pp = bpd + Pn * Dn;      // 4*P per-p params
  float* xb = pp + 4 * Pn;        // 2*B per-b params

  hipLaunchKernelGGL(prep_p_kernel, dim3(Pn), dim3(64), 0, stream, w, bias, bpd, pp);
  hipLaunchKernelGGL(prep_x_kernel, dim3(Bn / 4), dim3(256), 0, stream, x, xb);
  hipLaunchKernelGGL(main_kernel, dim3(Bn / BT, Pn / PT), dim3(512), 0, stream,
                     x, w, bpd, pp, xb, out);
}

// Round 8
// 32.183 us; speedup vs baseline: 2.8774x; 1.2402x over previous
//
#include <hip/hip_runtime.h>
#include <math.h>

namespace {
constexpr int Bn = 8192, Pn = 128, Dn = 128;
constexpr int BT = 64, PT = 32;                   // block tile: 64 b x 32 p
constexpr float MAXN = 1.0f - 1e-5f;              // (1-PROJ_EPS)/sqrt(c)
constexpr float CLAMPV = 16.63553233343869f;      // log(2/eps32)
constexpr float SMOOTH = 50.0f;
// bijective staggered row layout: row r starts at r*36 + ((r>>2)&3).
// bijective because stagger drop (<=3) < stride-32 (=4); read-conflict <= 2-way.
__device__ __forceinline__ int srow(int r) { return r * 36 + ((r >> 2) & 3); }
}

// ---------------- per-p prep: projected bias, cx, bw, 1/a_norm, lambda_p*a_norm
__global__ void prep_p_kernel(const float* __restrict__ weight,
                              const float* __restrict__ bias,
                              float* __restrict__ bp,
                              float* __restrict__ pp) {
  const int p = blockIdx.x;
  const int lane = threadIdx.x;  // 0..63
  const float* br = bias + p * Dn;
  const float* wr = weight + p * Dn;
  float b0 = br[lane], b1 = br[lane + 64];
  float w0 = wr[lane], w1 = wr[lane + 64];
  double nb2 = (double)b0 * b0 + (double)b1 * b1;
#pragma unroll
  for (int off = 32; off; off >>= 1) nb2 += __shfl_xor(nb2, off);
  double norm = sqrt(nb2);
  if (norm < 1e-15) norm = 1e-15;
  double scl = (norm > (double)MAXN) ? (double)MAXN / norm : 1.0;
  float bp0 = (float)((double)b0 * scl);
  float bp1 = (float)((double)b1 * scl);
  bp[p * Dn + lane] = bp0;
  bp[p * Dn + lane + 64] = bp1;
  double p2 = nb2 * scl * scl;
  double cx = 1.0 - p2;                 // coef_x = 1 - c*||p||^2
  double bwl = (double)bp0 * w0 + (double)bp1 * w1;
  double w2l = (double)w0 * w0 + (double)w1 * w1;
#pragma unroll
  for (int off = 32; off; off >>= 1) {
    bwl += __shfl_xor(bwl, off);
    w2l += __shfl_xor(w2l, off);
  }
  if (lane == 0) {
    double an = cx * sqrt(w2l);         // ||a|| = (1-p2)*||w||
    if (an < 1e-15) an = 1e-15;
    pp[p]          = (float)cx;
    pp[Pn + p]     = (float)bwl;        // <bias_proj, w>
    pp[2 * Pn + p] = (float)(1.0 / an);
    pp[3 * Pn + p] = (float)(2.0 / cx * an);  // lambda_p * a_norm
  }
}

// ---------------- per-b prep: x2 and 2/(1-x2), f64-accurate (1-x2 ~ 2e-5)
__global__ void prep_x_kernel(const float* __restrict__ x, float* __restrict__ xb) {
  const int row = blockIdx.x * 4 + (threadIdx.x >> 6);
  const int lane = threadIdx.x & 63;
  const float* xr = x + row * Dn;
  float x0 = xr[lane], x1 = xr[lane + 64];
  double s = (double)x0 * x0 + (double)x1 * x1;
#pragma unroll
  for (int off = 32; off; off >>= 1) s += __shfl_xor(s, off);
  if (lane == 0) {
    xb[row] = (float)s;
    xb[Bn + row] = (float)(2.0 / (1.0 - s));
  }
}

// ---------------- main: 64x32 tile, 512 threads = 4 k-teams of 128.
// Pure-LDS inner loop (all tiles in staggered stride-36 layout, <=2-way conflicts),
// micro 4(b) x 4(p), modest unroll (I$-friendly), merge via reused LDS,
// exact-region fast-path epilogue.
__global__ __launch_bounds__(512, 4)
void main_kernel(const float* __restrict__ x,
                 const float* __restrict__ weight,
                 const float* __restrict__ bpg,
                 const float* __restrict__ pp,
                 const float* __restrict__ xb,
                 float* __restrict__ out) {
  __shared__ float4 xs4[64 * 36];   // 36 KB
  __shared__ float4 ws4[32 * 36];   // 18 KB
  __shared__ float4 bs4[32 * 36];   // 18 KB -> 72 KB total, 2 blocks/CU

  const int tid = threadIdx.x;
  const int team = tid >> 7;            // 0..3 : k-quarter
  const int ti = tid & 127;
  const int tx = ti & 7;                // p-direction (micro 4)
  const int ty = ti >> 3;               // b-direction (micro 4), 0..15
  const int b0 = blockIdx.x * BT;
  const int p0 = blockIdx.y * PT;

  // ---- stage tiles; global reads coalesced; staggered bijective LDS layout
#pragma unroll
  for (int q = 0; q < 4; ++q) {
    int F = q * 512 + tid;
    int r = F >> 5, c = F & 31;
    xs4[srow(r) + c] =
        *reinterpret_cast<const float4*>(x + (size_t)(b0 + r) * Dn + c * 4);
  }
#pragma unroll
  for (int q = 0; q < 2; ++q) {
    int F = q * 512 + tid;
    int r = F >> 5, c = F & 31;
    ws4[srow(r) + c] =
        *reinterpret_cast<const float4*>(weight + (size_t)(p0 + r) * Dn + c * 4);
    bs4[srow(r) + c] =
        *reinterpret_cast<const float4*>(bpg + (size_t)(p0 + r) * Dn + c * 4);
  }
  __syncthreads();

  float accw[4][4] = {};
  float accb[4][4] = {};
  const int xoff = srow(4 * ty);    // row 4ty+i at xoff + i*36 (same stagger i<4)
  const int woff = srow(4 * tx);
  const int kb0 = team * 8;         // this team's k-quarter (float4 units)

#pragma unroll 2
  for (int kb = 0; kb < 8; ++kb) {
    const int k4 = kb0 + kb;
    float4 xf[4], wf[4], bf[4];
#pragma unroll
    for (int i = 0; i < 4; ++i) xf[i] = xs4[xoff + i * 36 + k4];
#pragma unroll
    for (int j = 0; j < 4; ++j) {
      wf[j] = ws4[woff + j * 36 + k4];
      bf[j] = bs4[woff + j * 36 + k4];
    }
#pragma unroll
    for (int i = 0; i < 4; ++i) {
#pragma unroll
      for (int j = 0; j < 4; ++j) {
        accw[i][j] = fmaf(xf[i].x, wf[j].x, accw[i][j]);
        accw[i][j] = fmaf(xf[i].y, wf[j].y, accw[i][j]);
        accw[i][j] = fmaf(xf[i].z, wf[j].z, accw[i][j]);
        accw[i][j] = fmaf(xf[i].w, wf[j].w, accw[i][j]);
        accb[i][j] = fmaf(xf[i].x, bf[j].x, accb[i][j]);
        accb[i][j] = fmaf(xf[i].y, bf[j].y, accb[i][j]);
        accb[i][j] = fmaf(xf[i].z, bf[j].z, accb[i][j]);
        accb[i][j] = fmaf(xf[i].w, bf[j].w, accb[i][j]);
      }
    }
  }

  // ---- merge k-quarters: teams 1,3 park in xs4; team 2 in ws4; team 0 sums.
  __syncthreads();
  if (team == 1 || team == 3) {
    int base = ((team >> 1) * 128 + ti) * 8;  // team1 -> 0.., team3 -> 1024..
#pragma unroll
    for (int i = 0; i < 4; ++i) {
      xs4[base + i]     = make_float4(accw[i][0], accw[i][1], accw[i][2], accw[i][3]);
      xs4[base + 4 + i] = make_float4(accb[i][0], accb[i][1], accb[i][2], accb[i][3]);
    }
  } else if (team == 2) {
    int base = ti * 8;
#pragma unroll
    for (int i = 0; i < 4; ++i) {
      ws4[base + i]     = make_float4(accw[i][0], accw[i][1], accw[i][2], accw[i][3]);
      ws4[base + 4 + i] = make_float4(accb[i][0], accb[i][1], accb[i][2], accb[i][3]);
    }
  }
  __syncthreads();

  if (team == 0) {
#pragma unroll
    for (int s = 0; s < 3; ++s) {
      const float4* src = (s == 2) ? &ws4[ti * 8] : &xs4[(s * 128 + ti) * 8];
#pragma unroll
      for (int i = 0; i < 4; ++i) {
        float4 pw = src[i], pb = src[4 + i];
        accw[i][0] += pw.x; accw[i][1] += pw.y; accw[i][2] += pw.z; accw[i][3] += pw.w;
        accb[i][0] += pb.x; accb[i][1] += pb.y; accb[i][2] += pb.z; accb[i][3] += pb.w;
      }
    }

    // ---- epilogue (exact-region fast-path; Mobius denominator cancels)
    float cxj[4], bwj[4], iaj[4], soj[4], x2i[4], fbi[4];
#pragma unroll
    for (int j = 0; j < 4; ++j) {
      int p = p0 + 4 * tx + j;
      cxj[j] = pp[p]; bwj[j] = pp[Pn + p]; iaj[j] = pp[2 * Pn + p]; soj[j] = pp[3 * Pn + p];
    }
#pragma unroll
    for (int i = 0; i < 4; ++i) {
      int b = b0 + 4 * ty + i;
      x2i[i] = xb[b]; fbi[i] = xb[Bn + b];
    }
#pragma unroll
    for (int i = 0; i < 4; ++i) {
      int b = b0 + 4 * ty + i;
      float res[4];
#pragma unroll
      for (int j = 0; j < 4; ++j) {
        float sb = accb[i][j];
        float xw = accw[i][j];
        float coefp = 1.0f + x2i[i] - 2.0f * sb;   // 1 + 2c*dot + c*x2
        float X = cxj[j] * xw - coefp * bwj[j];
        float arg = X * fbi[i] * iaj[j];           // den cancels analytically
        float aa = fabsf(arg);
        float argc;
        if (aa <= CLAMPV - 0.35f) {
          argc = aa;                                // smooth_clamp == identity (exact fp32)
        } else if (aa >= CLAMPV + 0.35f) {
          argc = CLAMPV;                            // fully clamped (exact fp32)
        } else {
          float z = SMOOTH * (aa - CLAMPV);         // band: softplus correction
          float sp = (fmaxf(z, 0.0f) + log1pf(expf(-fabsf(z)))) * (1.0f / SMOOTH);
          argc = aa - sp;
        }
        float r = logf(argc + sqrtf(fmaf(argc, argc, 1.0f)));  // asinh, z>=0
        res[j] = copysignf(soj[j] * r, arg);
      }
      *reinterpret_cast<float4*>(out + (size_t)b * Pn + p0 + 4 * tx) =
          make_float4(res[0], res[1], res[2], res[3]);
    }
  }
}

extern "C" void kernel_launch(void* const* d_in, const int* in_sizes, int n_in,
                              void* d_out, int out_size, void* d_ws, size_t ws_size,
                              hipStream_t stream) {
  const float* x = (const float*)d_in[0];
  const float* w = (const float*)d_in[1];
  const float* bias = (const float*)d_in[2];
  float* out = (float*)d_out;
  float* ws = (float*)d_ws;
  float* bpd = ws;                // [P][D] projected bias
  float* pp = bpd + Pn * Dn;      // 4*P per-p params
  float* xb = pp + 4 * Pn;        // 2*B per-b params

  hipLaunchKernelGGL(prep_p_kernel, dim3(Pn), dim3(64), 0, stream, w, bias, bpd, pp);
  hipLaunchKernelGGL(prep_x_kernel, dim3(Bn / 4), dim3(256), 0, stream, x, xb);
  hipLaunchKernelGGL(main_kernel, dim3(Bn / BT, Pn / PT), dim3(512), 0, stream,
                     x, w, bpd, pp, xb, out);
}

// Round 9
// 26.474 us; speedup vs baseline: 3.4978x; 1.2156x over previous
//
#include <hip/hip_runtime.h>
#include <math.h>

namespace {
constexpr int Bn = 8192, Pn = 128, Dn = 128;
constexpr int BT = 64, PT = 32;                   // block tile: 64 b x 32 p
constexpr float MAXN = 1.0f - 1e-5f;              // (1-PROJ_EPS)/sqrt(c)
constexpr float CLAMPV = 16.63553233343869f;      // log(2/eps32)
constexpr float SMOOTH = 50.0f;
// bijective staggered row layout: row r starts at r*36 + ((r>>2)&3).
// bijective (stagger drop <=3 < stride-32=4); fragment reads <=2-way conflict.
__device__ __forceinline__ int srow(int r) { return r * 36 + ((r >> 2) & 3); }
}

// ---------------- single fused kernel ----------------
// stage x/w/bias -> in-block f64 row stats -> scale bias in LDS ->
// pure-LDS dual-GEMM (4 k-teams, micro 4x4) -> merge -> fast-path epilogue.
__global__ __launch_bounds__(512, 4)
void fused_kernel(const float* __restrict__ x,
                  const float* __restrict__ weight,
                  const float* __restrict__ bias,
                  float* __restrict__ out) {
  __shared__ float4 xs4[64 * 36];   // 36 KB
  __shared__ float4 ws4[32 * 36];   // 18 KB
  __shared__ float4 bs4[32 * 36];   // 18 KB
  __shared__ float x2A[64], fbA[64];
  __shared__ float cxA[32], bwA[32], iaA[32], soA[32], sclA[32];

  const int tid = threadIdx.x;
  const int team = tid >> 7;            // 0..3 : k-quarter
  const int ti = tid & 127;
  const int tx = ti & 7;                // p-direction (micro 4)
  const int ty = ti >> 3;               // b-direction (micro 4), 0..15
  const int b0 = blockIdx.x * BT;
  const int p0 = blockIdx.y * PT;

  // ---- stage tiles (coalesced global reads, staggered bijective LDS layout)
#pragma unroll
  for (int q = 0; q < 4; ++q) {
    int F = q * 512 + tid;
    int r = F >> 5, c = F & 31;
    xs4[srow(r) + c] =
        *reinterpret_cast<const float4*>(x + (size_t)(b0 + r) * Dn + c * 4);
  }
#pragma unroll
  for (int q = 0; q < 2; ++q) {
    int F = q * 512 + tid;
    int r = F >> 5, c = F & 31;
    ws4[srow(r) + c] =
        *reinterpret_cast<const float4*>(weight + (size_t)(p0 + r) * Dn + c * 4);
    bs4[srow(r) + c] =
        *reinterpret_cast<const float4*>(bias + (size_t)(p0 + r) * Dn + c * 4);
  }
  __syncthreads();

  // ---- in-block f64 row stats (8 threads per row, shuffle-reduce within 8)
  {
    const int rr = tid >> 3, sub = tid & 7;
    // x rows: all 512 threads cover 64 rows
    {
      const float4* row = &xs4[srow(rr)];
      double s = 0.0;
#pragma unroll
      for (int q = 0; q < 4; ++q) {
        float4 v = row[sub + 8 * q];
        s += (double)v.x * v.x + (double)v.y * v.y +
             (double)v.z * v.z + (double)v.w * v.w;
      }
#pragma unroll
      for (int off = 1; off < 8; off <<= 1) s += __shfl_xor(s, off);
      if (sub == 0) {
        x2A[rr] = (float)s;
        fbA[rr] = (float)(2.0 / (1.0 - s));
      }
    }
    // p rows: threads 0..255 cover 32 rows (bias norm, <b,w>, w norm)
    if (tid < 256) {
      const float4* brow = &bs4[srow(rr)];
      const float4* wrow = &ws4[srow(rr)];
      double nb2 = 0.0, bwd = 0.0, w2 = 0.0;
#pragma unroll
      for (int q = 0; q < 4; ++q) {
        float4 b = brow[sub + 8 * q];
        float4 w = wrow[sub + 8 * q];
        nb2 += (double)b.x * b.x + (double)b.y * b.y +
               (double)b.z * b.z + (double)b.w * b.w;
        bwd += (double)b.x * w.x + (double)b.y * w.y +
               (double)b.z * w.z + (double)b.w * w.w;
        w2  += (double)w.x * w.x + (double)w.y * w.y +
               (double)w.z * w.z + (double)w.w * w.w;
      }
#pragma unroll
      for (int off = 1; off < 8; off <<= 1) {
        nb2 += __shfl_xor(nb2, off);
        bwd += __shfl_xor(bwd, off);
        w2  += __shfl_xor(w2, off);
      }
      if (sub == 0) {
        double norm = sqrt(nb2);
        if (norm < 1e-15) norm = 1e-15;
        double scl = (norm > (double)MAXN) ? (double)MAXN / norm : 1.0;
        double p2 = nb2 * scl * scl;
        double cx = 1.0 - p2;                 // coef_x = 1 - c*||p||^2
        double an = cx * sqrt(w2);            // ||a|| = (1-p2)*||w||
        if (an < 1e-15) an = 1e-15;
        cxA[rr]  = (float)cx;
        bwA[rr]  = (float)(scl * bwd);        // <bias_proj, w>
        iaA[rr]  = (float)(1.0 / an);
        soA[rr]  = (float)(2.0 / cx * an);    // lambda_p * a_norm
        sclA[rr] = (float)scl;
      }
    }
  }
  __syncthreads();

  // ---- scale bias tile in place: bias_proj = bias * scl(row)
#pragma unroll
  for (int q = 0; q < 2; ++q) {
    int F = q * 512 + tid;
    int r = F >> 5, c = F & 31;
    float s = sclA[r];
    float4 v = bs4[srow(r) + c];
    v.x *= s; v.y *= s; v.z *= s; v.w *= s;
    bs4[srow(r) + c] = v;
  }
  __syncthreads();

  // ---- pure-LDS dual-GEMM: micro 4(b) x 4(p), team k-quarter
  float accw[4][4] = {};
  float accb[4][4] = {};
  const int xoff = srow(4 * ty);    // rows 4ty..4ty+3 share stagger
  const int woff = srow(4 * tx);
  const int kb0 = team * 8;         // this team's k-quarter (float4 units)

#pragma unroll 2
  for (int kb = 0; kb < 8; ++kb) {
    const int k4 = kb0 + kb;
    float4 xf[4], wf[4], bf[4];
#pragma unroll
    for (int i = 0; i < 4; ++i) xf[i] = xs4[xoff + i * 36 + k4];
#pragma unroll
    for (int j = 0; j < 4; ++j) {
      wf[j] = ws4[woff + j * 36 + k4];
      bf[j] = bs4[woff + j * 36 + k4];
    }
#pragma unroll
    for (int i = 0; i < 4; ++i) {
#pragma unroll
      for (int j = 0; j < 4; ++j) {
        accw[i][j] = fmaf(xf[i].x, wf[j].x, accw[i][j]);
        accw[i][j] = fmaf(xf[i].y, wf[j].y, accw[i][j]);
        accw[i][j] = fmaf(xf[i].z, wf[j].z, accw[i][j]);
        accw[i][j] = fmaf(xf[i].w, wf[j].w, accw[i][j]);
        accb[i][j] = fmaf(xf[i].x, bf[j].x, accb[i][j]);
        accb[i][j] = fmaf(xf[i].y, bf[j].y, accb[i][j]);
        accb[i][j] = fmaf(xf[i].z, bf[j].z, accb[i][j]);
        accb[i][j] = fmaf(xf[i].w, bf[j].w, accb[i][j]);
      }
    }
  }

  // ---- merge k-quarters: teams 1,3 park in xs4; team 2 in ws4; team 0 sums.
  __syncthreads();
  if (team == 1 || team == 3) {
    int base = ((team >> 1) * 128 + ti) * 8;
#pragma unroll
    for (int i = 0; i < 4; ++i) {
      xs4[base + i]     = make_float4(accw[i][0], accw[i][1], accw[i][2], accw[i][3]);
      xs4[base + 4 + i] = make_float4(accb[i][0], accb[i][1], accb[i][2], accb[i][3]);
    }
  } else if (team == 2) {
    int base = ti * 8;
#pragma unroll
    for (int i = 0; i < 4; ++i) {
      ws4[base + i]     = make_float4(accw[i][0], accw[i][1], accw[i][2], accw[i][3]);
      ws4[base + 4 + i] = make_float4(accb[i][0], accb[i][1], accb[i][2], accb[i][3]);
    }
  }
  __syncthreads();

  if (team == 0) {
#pragma unroll
    for (int s = 0; s < 3; ++s) {
      const float4* src = (s == 2) ? &ws4[ti * 8] : &xs4[(s * 128 + ti) * 8];
#pragma unroll
      for (int i = 0; i < 4; ++i) {
        float4 pw = src[i], pb = src[4 + i];
        accw[i][0] += pw.x; accw[i][1] += pw.y; accw[i][2] += pw.z; accw[i][3] += pw.w;
        accb[i][0] += pb.x; accb[i][1] += pb.y; accb[i][2] += pb.z; accb[i][3] += pb.w;
      }
    }

    // ---- epilogue (exact-region fast-path; Mobius denominator cancels)
    float cxj[4], bwj[4], iaj[4], soj[4], x2i[4], fbi[4];
#pragma unroll
    for (int j = 0; j < 4; ++j) {
      int pl = 4 * tx + j;
      cxj[j] = cxA[pl]; bwj[j] = bwA[pl]; iaj[j] = iaA[pl]; soj[j] = soA[pl];
    }
#pragma unroll
    for (int i = 0; i < 4; ++i) {
      int bl = 4 * ty + i;
      x2i[i] = x2A[bl]; fbi[i] = fbA[bl];
    }
#pragma unroll
    for (int i = 0; i < 4; ++i) {
      int b = b0 + 4 * ty + i;
      float res[4];
#pragma unroll
      for (int j = 0; j < 4; ++j) {
        float sb = accb[i][j];
        float xw = accw[i][j];
        float coefp = 1.0f + x2i[i] - 2.0f * sb;   // 1 + 2c*dot + c*x2
        float X = cxj[j] * xw - coefp * bwj[j];
        float arg = X * fbi[i] * iaj[j];           // den cancels analytically
        float aa = fabsf(arg);
        float argc;
        if (aa <= CLAMPV - 0.35f) {
          argc = aa;                                // smooth_clamp == identity (exact fp32)
        } else if (aa >= CLAMPV + 0.35f) {
          argc = CLAMPV;                            // fully clamped (exact fp32)
        } else {
          float z = SMOOTH * (aa - CLAMPV);         // band: softplus correction
          float sp = (fmaxf(z, 0.0f) + log1pf(expf(-fabsf(z)))) * (1.0f / SMOOTH);
          argc = aa - sp;
        }
        float r = logf(argc + sqrtf(fmaf(argc, argc, 1.0f)));  // asinh, z>=0
        res[j] = copysignf(soj[j] * r, arg);
      }
      *reinterpret_cast<float4*>(out + (size_t)b * Pn + p0 + 4 * tx) =
          make_float4(res[0], res[1], res[2], res[3]);
    }
  }
}

extern "C" void kernel_launch(void* const* d_in, const int* in_sizes, int n_in,
                              void* d_out, int out_size, void* d_ws, size_t ws_size,
                              hipStream_t stream) {
  const float* x = (const float*)d_in[0];
  const float* w = (const float*)d_in[1];
  const float* bias = (const float*)d_in[2];
  float* out = (float*)d_out;

  hipLaunchKernelGGL(fused_kernel, dim3(Bn / BT, Pn / PT), dim3(512), 0, stream,
                     x, w, bias, out);
}

// Round 10
// 18.006 us; speedup vs baseline: 5.1427x; 1.4703x over previous
//
#include <hip/hip_runtime.h>
#include <math.h>

namespace {
constexpr int Bn = 8192, Pn = 128, Dn = 128;
constexpr int BT = 64, PT = 32;                   // block tile: 64 b x 32 p
constexpr float MAXN = 1.0f - 1e-5f;              // (1-PROJ_EPS)/sqrt(c)
constexpr float CLAMPV = 16.63553233343869f;      // log(2/eps32)
constexpr float SMOOTH = 50.0f;
// XOR-swizzled layout, stride 32 float4: slot(r,c) = r*32 + (c ^ ((r>>2)&7)).
// Fragment reads (fixed k, rows 4t..4t+3 across 8 lanes) hit 8 distinct
// bank-quads -> conflict-free; staging writes are row-contiguous.
__device__ __forceinline__ int slot(int r, int c) { return r * 32 + (c ^ ((r >> 2) & 7)); }
}

// ---------------- single fused kernel ----------------
// global->regs -> xs4/v-build (v = cx*w + k2*bias folds BOTH GEMMs into one)
// -> single-GEMM (4 k-teams, micro 4x4) -> park partials -> distributed epilogue.
__global__ __launch_bounds__(512, 4)
void fused_kernel(const float* __restrict__ x,
                  const float* __restrict__ weight,
                  const float* __restrict__ bias,
                  float* __restrict__ out) {
  __shared__ float4 xs4[64 * 32];   // 32 KB; reused as merge scratch (2048 slots)
  __shared__ float4 vs4[32 * 32];   // 16 KB
  __shared__ float x2A[64], fbA[64];
  __shared__ float bwA[32], iaA[32], soA[32];

  const int tid = threadIdx.x;
  const int team = tid >> 7;            // 0..3 : k-quarter
  const int ti = tid & 127;
  const int tx = ti & 7;                // p-direction (micro 4)
  const int ty = ti >> 3;               // b-direction (micro 4), 0..15
  const int b0 = blockIdx.x * BT;
  const int p0 = blockIdx.y * PT;
  const int rr = tid >> 5;              // 0..15: row within 16-row group
  const int cc = tid & 31;              // column chunk (float4)

  // ---- global loads, all issued up front (coalesced: 32 lanes span a row)
  float4 xv[4], wv[2], bv[2];
#pragma unroll
  for (int q = 0; q < 4; ++q)
    xv[q] = *reinterpret_cast<const float4*>(x + (size_t)(b0 + 16 * q + rr) * Dn + cc * 4);
#pragma unroll
  for (int q = 0; q < 2; ++q) {
    wv[q] = *reinterpret_cast<const float4*>(weight + (size_t)(p0 + 16 * q + rr) * Dn + cc * 4);
    bv[q] = *reinterpret_cast<const float4*>(bias + (size_t)(p0 + 16 * q + rr) * Dn + cc * 4);
  }

  // ---- stage x tile
#pragma unroll
  for (int q = 0; q < 4; ++q) xs4[slot(16 * q + rr, cc)] = xv[q];

  // ---- x-row stats: f64 butterfly all-reduce across the 32 lanes of each row
#pragma unroll
  for (int q = 0; q < 4; ++q) {
    float4 v = xv[q];
    double s = (double)v.x * v.x + (double)v.y * v.y +
               (double)v.z * v.z + (double)v.w * v.w;
#pragma unroll
    for (int off = 1; off < 32; off <<= 1) s += __shfl_xor(s, off);
    if (cc == 0) {
      x2A[16 * q + rr] = (float)s;
      fbA[16 * q + rr] = (float)(2.0 / (1.0 - s));
    }
  }

  // ---- p-row stats + v-build (all lanes hold row stats after butterfly)
#pragma unroll
  for (int q = 0; q < 2; ++q) {
    float4 w = wv[q], b = bv[q];
    double nb2 = (double)b.x * b.x + (double)b.y * b.y + (double)b.z * b.z + (double)b.w * b.w;
    double bwd = (double)b.x * w.x + (double)b.y * w.y + (double)b.z * w.z + (double)b.w * w.w;
    double w2  = (double)w.x * w.x + (double)w.y * w.y + (double)w.z * w.z + (double)w.w * w.w;
#pragma unroll
    for (int off = 1; off < 32; off <<= 1) {
      nb2 += __shfl_xor(nb2, off);
      bwd += __shfl_xor(bwd, off);
      w2  += __shfl_xor(w2, off);
    }
    double norm = sqrt(nb2);
    if (norm < 1e-15) norm = 1e-15;
    double scl = (norm > (double)MAXN) ? (double)MAXN / norm : 1.0;
    double p2 = nb2 * scl * scl;
    double cx = 1.0 - p2;                 // coef_x = 1 - c*||p||^2
    double bw = scl * bwd;                // <bias_proj, w>
    double an = cx * sqrt(w2);            // ||a|| = (1-p2)*||w||
    if (an < 1e-15) an = 1e-15;
    const float cxf = (float)cx;
    const float k2f = (float)(2.0 * bw * scl);
    float4 v;
    v.x = fmaf(cxf, w.x, k2f * b.x);
    v.y = fmaf(cxf, w.y, k2f * b.y);
    v.z = fmaf(cxf, w.z, k2f * b.z);
    v.w = fmaf(cxf, w.w, k2f * b.w);
    vs4[slot(16 * q + rr, cc)] = v;
    if (cc == 0) {
      int r = 16 * q + rr;
      bwA[r] = (float)bw;
      iaA[r] = (float)(1.0 / an);
      soA[r] = (float)(2.0 / cx * an);    // lambda_p * a_norm
    }
  }
  __syncthreads();

  // ---- single-GEMM main loop: micro 4(b) x 4(p), team k-quarter, pure LDS
  float acc[4][4] = {};
  const int swx = ty & 7;     // (4ty+i)>>2 & 7 == ty&7 for i<4
  const int swv = tx & 7;
#pragma unroll 2
  for (int kb = 0; kb < 8; ++kb) {
    const int k4 = team * 8 + kb;
    float4 xf[4], vf[4];
#pragma unroll
    for (int i = 0; i < 4; ++i) xf[i] = xs4[(4 * ty + i) * 32 + (k4 ^ swx)];
#pragma unroll
    for (int j = 0; j < 4; ++j) vf[j] = vs4[(4 * tx + j) * 32 + (k4 ^ swv)];
#pragma unroll
    for (int i = 0; i < 4; ++i) {
#pragma unroll
      for (int j = 0; j < 4; ++j) {
        acc[i][j] = fmaf(xf[i].x, vf[j].x, acc[i][j]);
        acc[i][j] = fmaf(xf[i].y, vf[j].y, acc[i][j]);
        acc[i][j] = fmaf(xf[i].z, vf[j].z, acc[i][j]);
        acc[i][j] = fmaf(xf[i].w, vf[j].w, acc[i][j]);
      }
    }
  }

  // ---- park ALL partials (xs4 dead): layout [i][tid] -> contiguous lanes
  __syncthreads();
#pragma unroll
  for (int i = 0; i < 4; ++i)
    xs4[i * 512 + tid] = make_float4(acc[i][0], acc[i][1], acc[i][2], acc[i][3]);
  __syncthreads();

  // ---- distributed epilogue: thread (team, ti) owns row b0 + 4*ty + team
  {
    float sum[4];
    {
      float4 s0 = xs4[team * 512 + 0 * 128 + ti];
      float4 s1 = xs4[team * 512 + 1 * 128 + ti];
      float4 s2 = xs4[team * 512 + 2 * 128 + ti];
      float4 s3 = xs4[team * 512 + 3 * 128 + ti];
      sum[0] = (s0.x + s1.x) + (s2.x + s3.x);
      sum[1] = (s0.y + s1.y) + (s2.y + s3.y);
      sum[2] = (s0.z + s1.z) + (s2.z + s3.z);
      sum[3] = (s0.w + s1.w) + (s2.w + s3.w);
    }
    const int bl = 4 * ty + team;
    const int b = b0 + bl;
    const float x2i = x2A[bl];
    const float fbi = fbA[bl];
    const float opx = 1.0f + x2i;
    float res[4];
#pragma unroll
    for (int j = 0; j < 4; ++j) {
      int pl = 4 * tx + j;
      float X = fmaf(-opx, bwA[pl], sum[j]);     // <x,v> - (1+x2)*bw
      float arg = X * fbi * iaA[pl];             // Mobius denominator cancels
      float aa = fabsf(arg);
      float argc;
      if (aa <= CLAMPV - 0.35f) {
        argc = aa;                                // smooth_clamp == identity (exact fp32)
      } else if (aa >= CLAMPV + 0.35f) {
        argc = CLAMPV;                            // fully clamped (exact fp32)
      } else {
        float z = SMOOTH * (aa - CLAMPV);         // transition band: softplus corr
        float sp = (fmaxf(z, 0.0f) + log1pf(expf(-fabsf(z)))) * (1.0f / SMOOTH);
        argc = aa - sp;
      }
      float r = logf(argc + sqrtf(fmaf(argc, argc, 1.0f)));  // asinh, z>=0
      res[j] = copysignf(soA[pl] * r, arg);
    }
    *reinterpret_cast<float4*>(out + (size_t)b * Pn + p0 + 4 * tx) =
        make_float4(res[0], res[1], res[2], res[3]);
  }
}

extern "C" void kernel_launch(void* const* d_in, const int* in_sizes, int n_in,
                              void* d_out, int out_size, void* d_ws, size_t ws_size,
                              hipStream_t stream) {
  const float* x = (const float*)d_in[0];
  const float* w = (const float*)d_in[1];
  const float* bias = (const float*)d_in[2];
  float* out = (float*)d_out;

  hipLaunchKernelGGL(fused_kernel, dim3(Bn / BT, Pn / PT), dim3(512), 0, stream,
                     x, w, bias, out);
}

// Round 11
// 17.888 us; speedup vs baseline: 5.1767x; 1.0066x over previous
//
#include <hip/hip_runtime.h>
#include <math.h>

namespace {
constexpr int Bn = 8192, Pn = 128, Dn = 128;
constexpr int BT = 64, PT = 32;                   // block tile: 64 b x 32 p
constexpr float MAXN = 1.0f - 1e-5f;              // (1-PROJ_EPS)/sqrt(c)
constexpr float CLAMPV = 16.63553233343869f;      // log(2/eps32)
constexpr float SMOOTH = 50.0f;
// XOR-swizzled layout, stride 32 float4: slot(r,c) = r*32 + (c ^ ((r>>2)&7)).
// Fragment reads (fixed k, rows 4t..4t+3 across 8 lanes) hit 8 distinct
// bank-quads -> conflict-free; staging writes are row-contiguous.
__device__ __forceinline__ int slot(int r, int c) { return r * 32 + (c ^ ((r >> 2) & 7)); }
}

// load fragment set for k4-step (compile-time-static register names)
#define LOADSET(k4, X0, X1, X2, X3, V0, V1, V2, V3)            \
  {                                                            \
    const int kx_ = (k4) ^ swx;                                \
    const int kv_ = (k4) ^ swv;                                \
    X0 = xs4[xbase + 0 * 32 + kx_];                            \
    X1 = xs4[xbase + 1 * 32 + kx_];                            \
    X2 = xs4[xbase + 2 * 32 + kx_];                            \
    X3 = xs4[xbase + 3 * 32 + kx_];                            \
    V0 = vs4[vbase + 0 * 32 + kv_];                            \
    V1 = vs4[vbase + 1 * 32 + kv_];                            \
    V2 = vs4[vbase + 2 * 32 + kv_];                            \
    V3 = vs4[vbase + 3 * 32 + kv_];                            \
  }

#define FMASET(X0, X1, X2, X3, V0, V1, V2, V3)                 \
  {                                                            \
    float4 xf_[4] = {X0, X1, X2, X3};                          \
    float4 vf_[4] = {V0, V1, V2, V3};                          \
    _Pragma("unroll") for (int i = 0; i < 4; ++i) {            \
      _Pragma("unroll") for (int j = 0; j < 4; ++j) {          \
        acc[i][j] = fmaf(xf_[i].x, vf_[j].x, acc[i][j]);       \
        acc[i][j] = fmaf(xf_[i].y, vf_[j].y, acc[i][j]);       \
        acc[i][j] = fmaf(xf_[i].z, vf_[j].z, acc[i][j]);       \
        acc[i][j] = fmaf(xf_[i].w, vf_[j].w, acc[i][j]);       \
      }                                                        \
    }                                                          \
  }

// ---------------- single fused kernel ----------------
// global->regs -> xs4/v-build (v = cx*w + k2*bias folds BOTH GEMMs into one)
// -> single-GEMM (4 k-teams, 2-deep pipelined, micro 4x4) -> park -> epilogue.
__global__ __launch_bounds__(512, 4)
void fused_kernel(const float* __restrict__ x,
                  const float* __restrict__ weight,
                  const float* __restrict__ bias,
                  float* __restrict__ out) {
  __shared__ float4 xs4[64 * 32];   // 32 KB; reused as merge scratch (2048 slots)
  __shared__ float4 vs4[32 * 32];   // 16 KB
  __shared__ float x2A[64], fbA[64];
  __shared__ float bwA[32], iaA[32], soA[32];

  const int tid = threadIdx.x;
  const int team = tid >> 7;            // 0..3 : k-quarter
  const int ti = tid & 127;
  const int tx = ti & 7;                // p-direction (micro 4)
  const int ty = ti >> 3;               // b-direction (micro 4), 0..15
  const int b0 = blockIdx.x * BT;
  const int p0 = blockIdx.y * PT;
  const int rr = tid >> 5;              // 0..15: row within 16-row group
  const int cc = tid & 31;              // column chunk (float4)

  // ---- global loads, all issued up front (coalesced: 32 lanes span a row)
  float4 xv[4], wv[2], bv[2];
#pragma unroll
  for (int q = 0; q < 4; ++q)
    xv[q] = *reinterpret_cast<const float4*>(x + (size_t)(b0 + 16 * q + rr) * Dn + cc * 4);
#pragma unroll
  for (int q = 0; q < 2; ++q) {
    wv[q] = *reinterpret_cast<const float4*>(weight + (size_t)(p0 + 16 * q + rr) * Dn + cc * 4);
    bv[q] = *reinterpret_cast<const float4*>(bias + (size_t)(p0 + 16 * q + rr) * Dn + cc * 4);
  }

  // ---- stage x tile
#pragma unroll
  for (int q = 0; q < 4; ++q) xs4[slot(16 * q + rr, cc)] = xv[q];

  // ---- x-row stats: f64 butterfly all-reduce across the 32 lanes of each row
#pragma unroll
  for (int q = 0; q < 4; ++q) {
    float4 v = xv[q];
    double s = (double)v.x * v.x + (double)v.y * v.y +
               (double)v.z * v.z + (double)v.w * v.w;
#pragma unroll
    for (int off = 1; off < 32; off <<= 1) s += __shfl_xor(s, off);
    if (cc == 0) {
      x2A[16 * q + rr] = (float)s;
      fbA[16 * q + rr] = (float)(2.0 / (1.0 - s));
    }
  }

  // ---- p-row stats + v-build (all lanes hold row stats after butterfly)
#pragma unroll
  for (int q = 0; q < 2; ++q) {
    float4 w = wv[q], b = bv[q];
    double nb2 = (double)b.x * b.x + (double)b.y * b.y + (double)b.z * b.z + (double)b.w * b.w;
    double bwd = (double)b.x * w.x + (double)b.y * w.y + (double)b.z * w.z + (double)b.w * w.w;
    double w2  = (double)w.x * w.x + (double)w.y * w.y + (double)w.z * w.z + (double)w.w * w.w;
#pragma unroll
    for (int off = 1; off < 32; off <<= 1) {
      nb2 += __shfl_xor(nb2, off);
      bwd += __shfl_xor(bwd, off);
      w2  += __shfl_xor(w2, off);
    }
    double norm = sqrt(nb2);
    if (norm < 1e-15) norm = 1e-15;
    double scl = (norm > (double)MAXN) ? (double)MAXN / norm : 1.0;
    double p2 = nb2 * scl * scl;
    double cx = 1.0 - p2;                 // coef_x = 1 - c*||p||^2
    double bw = scl * bwd;                // <bias_proj, w>
    double an = cx * sqrt(w2);            // ||a|| = (1-p2)*||w||
    if (an < 1e-15) an = 1e-15;
    const float cxf = (float)cx;
    const float k2f = (float)(2.0 * bw * scl);
    float4 v;
    v.x = fmaf(cxf, w.x, k2f * b.x);
    v.y = fmaf(cxf, w.y, k2f * b.y);
    v.z = fmaf(cxf, w.z, k2f * b.z);
    v.w = fmaf(cxf, w.w, k2f * b.w);
    vs4[slot(16 * q + rr, cc)] = v;
    if (cc == 0) {
      int r = 16 * q + rr;
      bwA[r] = (float)bw;
      iaA[r] = (float)(1.0 / an);
      soA[r] = (float)(2.0 / cx * an);    // lambda_p * a_norm
    }
  }
  __syncthreads();

  // ---- single-GEMM main loop: micro 4(b) x 4(p), team k-quarter, pure LDS,
  // 2-deep named-register pipeline (loads of step k+1 issue under FMAs of k)
  float acc[4][4] = {};
  const int swx = ty & 7;     // (4ty+i)>>2 & 7 == ty&7 for i<4
  const int swv = tx & 7;
  const int xbase = (4 * ty) * 32;
  const int vbase = (4 * tx) * 32;
  const int k0 = team * 8;

  float4 xA0, xA1, xA2, xA3, vA0, vA1, vA2, vA3;
  float4 xB0, xB1, xB2, xB3, vB0, vB1, vB2, vB3;

  LOADSET(k0 + 0, xA0, xA1, xA2, xA3, vA0, vA1, vA2, vA3);
  LOADSET(k0 + 1, xB0, xB1, xB2, xB3, vB0, vB1, vB2, vB3);
  FMASET(xA0, xA1, xA2, xA3, vA0, vA1, vA2, vA3);
  LOADSET(k0 + 2, xA0, xA1, xA2, xA3, vA0, vA1, vA2, vA3);
  FMASET(xB0, xB1, xB2, xB3, vB0, vB1, vB2, vB3);
  LOADSET(k0 + 3, xB0, xB1, xB2, xB3, vB0, vB1, vB2, vB3);
  FMASET(xA0, xA1, xA2, xA3, vA0, vA1, vA2, vA3);
  LOADSET(k0 + 4, xA0, xA1, xA2, xA3, vA0, vA1, vA2, vA3);
  FMASET(xB0, xB1, xB2, xB3, vB0, vB1, vB2, vB3);
  LOADSET(k0 + 5, xB0, xB1, xB2, xB3, vB0, vB1, vB2, vB3);
  FMASET(xA0, xA1, xA2, xA3, vA0, vA1, vA2, vA3);
  LOADSET(k0 + 6, xA0, xA1, xA2, xA3, vA0, vA1, vA2, vA3);
  FMASET(xB0, xB1, xB2, xB3, vB0, vB1, vB2, vB3);
  LOADSET(k0 + 7, xB0, xB1, xB2, xB3, vB0, vB1, vB2, vB3);
  FMASET(xA0, xA1, xA2, xA3, vA0, vA1, vA2, vA3);
  FMASET(xB0, xB1, xB2, xB3, vB0, vB1, vB2, vB3);

  // ---- park ALL partials (xs4 dead): layout [i][tid] -> contiguous lanes
  __syncthreads();
#pragma unroll
  for (int i = 0; i < 4; ++i)
    xs4[i * 512 + tid] = make_float4(acc[i][0], acc[i][1], acc[i][2], acc[i][3]);
  __syncthreads();

  // ---- distributed epilogue: thread (team, ti) owns row b0 + 4*ty + team
  {
    float sum[4];
    {
      float4 s0 = xs4[team * 512 + 0 * 128 + ti];
      float4 s1 = xs4[team * 512 + 1 * 128 + ti];
      float4 s2 = xs4[team * 512 + 2 * 128 + ti];
      float4 s3 = xs4[team * 512 + 3 * 128 + ti];
      sum[0] = (s0.x + s1.x) + (s2.x + s3.x);
      sum[1] = (s0.y + s1.y) + (s2.y + s3.y);
      sum[2] = (s0.z + s1.z) + (s2.z + s3.z);
      sum[3] = (s0.w + s1.w) + (s2.w + s3.w);
    }
    const int bl = 4 * ty + team;
    const int b = b0 + bl;
    const float x2i = x2A[bl];
    const float fbi = fbA[bl];
    const float opx = 1.0f + x2i;
    float res[4];
#pragma unroll
    for (int j = 0; j < 4; ++j) {
      int pl = 4 * tx + j;
      float X = fmaf(-opx, bwA[pl], sum[j]);     // <x,v> - (1+x2)*bw
      float arg = X * fbi * iaA[pl];             // Mobius denominator cancels
      float aa = fabsf(arg);
      float argc;
      if (aa <= CLAMPV - 0.35f) {
        argc = aa;                                // smooth_clamp == identity (exact fp32)
      } else if (aa >= CLAMPV + 0.35f) {
        argc = CLAMPV;                            // fully clamped (exact fp32)
      } else {
        float z = SMOOTH * (aa - CLAMPV);         // transition band: softplus corr
        float sp = (fmaxf(z, 0.0f) + log1pf(expf(-fabsf(z)))) * (1.0f / SMOOTH);
        argc = aa - sp;
      }
      float r = logf(argc + sqrtf(fmaf(argc, argc, 1.0f)));  // asinh, z>=0
      res[j] = copysignf(soA[pl] * r, arg);
    }
    *reinterpret_cast<float4*>(out + (size_t)b * Pn + p0 + 4 * tx) =
        make_float4(res[0], res[1], res[2], res[3]);
  }
}

extern "C" void kernel_launch(void* const* d_in, const int* in_sizes, int n_in,
                              void* d_out, int out_size, void* d_ws, size_t ws_size,
                              hipStream_t stream) {
  const float* x = (const float*)d_in[0];
  const float* w = (const float*)d_in[1];
  const float* bias = (const float*)d_in[2];
  float* out = (float*)d_out;

  hipLaunchKernelGGL(fused_kernel, dim3(Bn / BT, Pn / PT), dim3(512), 0, stream,
                     x, w, bias, out);
}

// Round 12
// 15.090 us; speedup vs baseline: 6.1366x; 1.1854x over previous
//
#include <hip/hip_runtime.h>
#include <math.h>

namespace {
constexpr int Bn = 8192, Pn = 128, Dn = 128;
constexpr int BT = 64, PT = 32;                   // block tile: 64 b x 32 p
constexpr float MAXN = 1.0f - 1e-5f;              // (1-PROJ_EPS)/sqrt(c)
constexpr float CLAMPV = 16.63553233343869f;      // log(2/eps32)
constexpr float SMOOTH = 50.0f;
// XOR-swizzled layout, stride 32 float4: slot(r,c) = r*32 + (c ^ ((r>>2)&7)).
__device__ __forceinline__ int slot(int r, int c) { return r * 32 + (c ^ ((r >> 2) & 7)); }
}

// ---------------- single fused kernel ----------------
// global->regs -> f64 partials to LDS scratch (aliasing tiles, pre-staging)
// -> tree reduce (no shfl butterflies) -> stage x + v-build
// -> single-GEMM (4 k-teams, micro 4x4) -> park -> distributed epilogue.
__global__ __launch_bounds__(512, 4)
void fused_kernel(const float* __restrict__ x,
                  const float* __restrict__ weight,
                  const float* __restrict__ bias,
                  float* __restrict__ out) {
  __shared__ float4 xs4[64 * 32];   // 32 KB; pre-staging: p-partial scratch; post-GEMM: merge
  __shared__ float4 vs4[32 * 32];   // 16 KB; pre-staging: x-partial scratch
  __shared__ double psum[96];
  __shared__ float x2A[64], fbA[64];
  __shared__ float cxA[32], k2A[32], bwA[32], iaA[32], soA[32];

  double* const scratchP = reinterpret_cast<double*>(xs4);   // 6 x 512 f64 (24 KB)
  double* const scratchX = reinterpret_cast<double*>(vs4);   // 4 x 512 f64 (16 KB)

  const int tid = threadIdx.x;
  const int team = tid >> 7;            // 0..3 : k-quarter
  const int ti = tid & 127;
  const int tx = ti & 7;                // p-direction (micro 4)
  const int ty = ti >> 3;               // b-direction (micro 4), 0..15
  const int b0 = blockIdx.x * BT;
  const int p0 = blockIdx.y * PT;
  const int rr = tid >> 5;              // 0..15: row within 16-row group
  const int cc = tid & 31;              // column chunk (float4)

  // ---- global loads, all issued up front (coalesced: 32 lanes span a row)
  float4 xv[4], wv[2], bv[2];
#pragma unroll
  for (int q = 0; q < 4; ++q)
    xv[q] = *reinterpret_cast<const float4*>(x + (size_t)(b0 + 16 * q + rr) * Dn + cc * 4);
#pragma unroll
  for (int q = 0; q < 2; ++q) {
    wv[q] = *reinterpret_cast<const float4*>(weight + (size_t)(p0 + 16 * q + rr) * Dn + cc * 4);
    bv[q] = *reinterpret_cast<const float4*>(bias + (size_t)(p0 + 16 * q + rr) * Dn + cc * 4);
  }

  // ---- f64 per-lane partials into SoA scratch (conflict-free b64 writes)
#pragma unroll
  for (int q = 0; q < 2; ++q) {
    float4 w = wv[q], b = bv[q];
    double nb2 = (double)b.x * b.x + (double)b.y * b.y + (double)b.z * b.z + (double)b.w * b.w;
    double bwd = (double)b.x * w.x + (double)b.y * w.y + (double)b.z * w.z + (double)b.w * w.w;
    double w2  = (double)w.x * w.x + (double)w.y * w.y + (double)w.z * w.z + (double)w.w * w.w;
    scratchP[(q * 3 + 0) * 512 + tid] = nb2;
    scratchP[(q * 3 + 1) * 512 + tid] = bwd;
    scratchP[(q * 3 + 2) * 512 + tid] = w2;
  }
#pragma unroll
  for (int q = 0; q < 4; ++q) {
    float4 v = xv[q];
    scratchX[q * 512 + tid] =
        (double)v.x * v.x + (double)v.y * v.y + (double)v.z * v.z + (double)v.w * v.w;
  }
  __syncthreads();

  // ---- tree reduce: 96 threads for p (row,val), 64 threads (wave 4) for x rows
  if (tid < 96) {
    const int row = tid / 3;                      // 0..31
    const int val = tid - row * 3;                // tid == row*3 + val
    const double2* sp = reinterpret_cast<const double2*>(
        scratchP + (size_t)(((row >> 4) * 3 + val) * 512 + (row & 15) * 32));
    const int j0 = tid & 15;                      // stagger to spread banks
    double a0 = 0, a1 = 0, a2 = 0, a3 = 0;
#pragma unroll
    for (int i = 0; i < 16; i += 4) {
      double2 d0 = sp[(j0 + i) & 15], d1 = sp[(j0 + i + 1) & 15];
      double2 d2 = sp[(j0 + i + 2) & 15], d3 = sp[(j0 + i + 3) & 15];
      a0 += d0.x + d0.y; a1 += d1.x + d1.y; a2 += d2.x + d2.y; a3 += d3.x + d3.y;
    }
    psum[tid] = (a0 + a1) + (a2 + a3);
  } else if (tid >= 256 && tid < 320) {
    const int r = tid - 256;                      // 0..63: b-row in tile
    const double2* sp = reinterpret_cast<const double2*>(
        scratchX + (size_t)((r >> 4) * 512 + (r & 15) * 32));
    const int j0 = tid & 15;
    double a0 = 0, a1 = 0, a2 = 0, a3 = 0;
#pragma unroll
    for (int i = 0; i < 16; i += 4) {
      double2 d0 = sp[(j0 + i) & 15], d1 = sp[(j0 + i + 1) & 15];
      double2 d2 = sp[(j0 + i + 2) & 15], d3 = sp[(j0 + i + 3) & 15];
      a0 += d0.x + d0.y; a1 += d1.x + d1.y; a2 += d2.x + d2.y; a3 += d3.x + d3.y;
    }
    double s = (a0 + a1) + (a2 + a3);
    x2A[r] = (float)s;
    fbA[r] = (float)(2.0 / (1.0 - s));
  }
  __syncthreads();

  // ---- finalize p-params (32 threads)
  if (tid < 32) {
    double nb2 = psum[tid * 3 + 0];
    double bwd = psum[tid * 3 + 1];
    double w2  = psum[tid * 3 + 2];
    double norm = sqrt(nb2);
    if (norm < 1e-15) norm = 1e-15;
    double scl = (norm > (double)MAXN) ? (double)MAXN / norm : 1.0;
    double p2 = nb2 * scl * scl;
    double cx = 1.0 - p2;                 // coef_x = 1 - c*||p||^2
    double bw = scl * bwd;                // <bias_proj, w>
    double an = cx * sqrt(w2);            // ||a|| = (1-p2)*||w||
    if (an < 1e-15) an = 1e-15;
    cxA[tid] = (float)cx;
    k2A[tid] = (float)(2.0 * bw * scl);
    bwA[tid] = (float)bw;
    iaA[tid] = (float)(1.0 / an);
    soA[tid] = (float)(2.0 / cx * an);    // lambda_p * a_norm
  }
  __syncthreads();

  // ---- stage x tile + build v tile (scratch regions now dead)
#pragma unroll
  for (int q = 0; q < 4; ++q) xs4[slot(16 * q + rr, cc)] = xv[q];
#pragma unroll
  for (int q = 0; q < 2; ++q) {
    const int r = 16 * q + rr;
    const float cxf = cxA[r];
    const float k2f = k2A[r];
    float4 w = wv[q], b = bv[q], v;
    v.x = fmaf(cxf, w.x, k2f * b.x);
    v.y = fmaf(cxf, w.y, k2f * b.y);
    v.z = fmaf(cxf, w.z, k2f * b.z);
    v.w = fmaf(cxf, w.w, k2f * b.w);
    vs4[slot(r, cc)] = v;
  }
  __syncthreads();

  // ---- single-GEMM main loop: micro 4(b) x 4(p), team k-quarter, pure LDS
  float acc[4][4] = {};
  const int swx = ty & 7;     // (4ty+i)>>2 & 7 == ty&7 for i<4
  const int swv = tx & 7;
#pragma unroll 2
  for (int kb = 0; kb < 8; ++kb) {
    const int k4 = team * 8 + kb;
    float4 xf[4], vf[4];
#pragma unroll
    for (int i = 0; i < 4; ++i) xf[i] = xs4[(4 * ty + i) * 32 + (k4 ^ swx)];
#pragma unroll
    for (int j = 0; j < 4; ++j) vf[j] = vs4[(4 * tx + j) * 32 + (k4 ^ swv)];
#pragma unroll
    for (int i = 0; i < 4; ++i) {
#pragma unroll
      for (int j = 0; j < 4; ++j) {
        acc[i][j] = fmaf(xf[i].x, vf[j].x, acc[i][j]);
        acc[i][j] = fmaf(xf[i].y, vf[j].y, acc[i][j]);
        acc[i][j] = fmaf(xf[i].z, vf[j].z, acc[i][j]);
        acc[i][j] = fmaf(xf[i].w, vf[j].w, acc[i][j]);
      }
    }
  }

  // ---- park ALL partials (xs4 dead): layout [i][tid] -> contiguous lanes
  __syncthreads();
#pragma unroll
  for (int i = 0; i < 4; ++i)
    xs4[i * 512 + tid] = make_float4(acc[i][0], acc[i][1], acc[i][2], acc[i][3]);
  __syncthreads();

  // ---- distributed epilogue: thread (team, ti) owns row b0 + 4*ty + team
  {
    float sum[4];
    {
      float4 s0 = xs4[team * 512 + 0 * 128 + ti];
      float4 s1 = xs4[team * 512 + 1 * 128 + ti];
      float4 s2 = xs4[team * 512 + 2 * 128 + ti];
      float4 s3 = xs4[team * 512 + 3 * 128 + ti];
      sum[0] = (s0.x + s1.x) + (s2.x + s3.x);
      sum[1] = (s0.y + s1.y) + (s2.y + s3.y);
      sum[2] = (s0.z + s1.z) + (s2.z + s3.z);
      sum[3] = (s0.w + s1.w) + (s2.w + s3.w);
    }
    const int bl = 4 * ty + team;
    const int b = b0 + bl;
    const float x2i = x2A[bl];
    const float fbi = fbA[bl];
    const float opx = 1.0f + x2i;
    float res[4];
#pragma unroll
    for (int j = 0; j < 4; ++j) {
      int pl = 4 * tx + j;
      float X = fmaf(-opx, bwA[pl], sum[j]);     // <x,v> - (1+x2)*bw
      float arg = X * fbi * iaA[pl];             // Mobius denominator cancels
      float aa = fabsf(arg);
      float argc;
      if (aa <= CLAMPV - 0.35f) {
        argc = aa;                                // smooth_clamp == identity (exact fp32)
      } else if (aa >= CLAMPV + 0.35f) {
        argc = CLAMPV;                            // fully clamped (exact fp32)
      } else {
        float z = SMOOTH * (aa - CLAMPV);         // transition band: softplus corr
        float sp = (fmaxf(z, 0.0f) + log1pf(__expf(-fabsf(z)))) * (1.0f / SMOOTH);
        argc = aa - sp;
      }
      float r = __logf(argc + sqrtf(fmaf(argc, argc, 1.0f)));  // asinh, z>=0
      res[j] = copysignf(soA[pl] * r, arg);
    }
    *reinterpret_cast<float4*>(out + (size_t)b * Pn + p0 + 4 * tx) =
        make_float4(res[0], res[1], res[2], res[3]);
  }
}

extern "C" void kernel_launch(void* const* d_in, const int* in_sizes, int n_in,
                              void* d_out, int out_size, void* d_ws, size_t ws_size,
                              hipStream_t stream) {
  const float* x = (const float*)d_in[0];
  const float* w = (const float*)d_in[1];
  const float* bias = (const float*)d_in[2];
  float* out = (float*)d_out;

  hipLaunchKernelGGL(fused_kernel, dim3(Bn / BT, Pn / PT), dim3(512), 0, stream,
                     x, w, bias, out);
}